// Round 2
// baseline (574.817 us; speedup 1.0000x reference)
//
#include <hip/hip_runtime.h>

#define M_DIM 4096
#define N_DIM 8192
#define K_DIM 2048
#define NGRP 16
#define GSZ 512
#define EPSV 1e-5f

typedef __attribute__((ext_vector_type(8))) short bf16x8;
typedef __attribute__((ext_vector_type(4))) float f32x4;

__device__ __forceinline__ float b2f(short u) {
    union { unsigned u32; float f; } c;
    c.u32 = ((unsigned)(unsigned short)u) << 16;
    return c.f;
}

__device__ __forceinline__ short f2b(float f) {
    union { float f; unsigned u; } c; c.f = f;
    unsigned r = (c.u + 0x7fffu + ((c.u >> 16) & 1u)) >> 16;
    return (short)r;
}

// dtype flag: gn_w is all ones. bf16: word0 = 0x3F803F80 ; fp32: 0x3F800000.
__device__ __forceinline__ bool detect_bf16(const void* gnw) {
    return ((const unsigned*)gnw)[0] == 0x3F803F80u;
}

// C[M][N] = A[M][K] @ W[N][K]^T. Inputs bf16 OR fp32 (device-detected).
// Compute core: bf16 LDS tiles (128x128 tile, BK=32), mfma_f32_16x16x32_bf16,
// 4 waves x 64x64 quadrant, 4x4 fragments. Staging: vector load -> ds_write.
__global__ __launch_bounds__(256) void gemm_bt_kernel(
    const void* __restrict__ A_, const void* __restrict__ W_,
    void* __restrict__ C_, const void* __restrict__ flagsrc)
{
    __shared__ __align__(16) short ldsA[128 * 32];
    __shared__ __align__(16) short ldsB[128 * 32];

    const bool isbf = detect_bf16(flagsrc);

    const int tid  = threadIdx.x;
    const int lane = tid & 63;
    const int wave = tid >> 6;
    const int blockRow = blockIdx.y * 128;
    const int blockCol = blockIdx.x * 128;

    // staging: thread t covers tile row (t>>1), k-cols (t&1)*16 .. +15 of BOTH tiles
    const int srow = tid >> 1;
    const int scol = (tid & 1) * 16;

    // compute decomposition
    const int wm  = (wave >> 1) * 64;
    const int wn  = (wave & 1) * 64;
    const int fr  = lane & 15;        // m (or n) within 16x16 tile
    const int fko = (lane >> 4) * 8;  // k offset for fragment

    f32x4 acc[4][4] = {};

    const size_t aRowOff = (size_t)(blockRow + srow) * K_DIM;
    const size_t wRowOff = (size_t)(blockCol + srow) * K_DIM;

    for (int k0 = 0; k0 < K_DIM; k0 += 32) {
        if (isbf) {
            const short* Ab = (const short*)A_;
            const short* Wb = (const short*)W_;
            bf16x8 a0 = *(const bf16x8*)(Ab + aRowOff + k0 + scol);
            bf16x8 a1 = *(const bf16x8*)(Ab + aRowOff + k0 + scol + 8);
            bf16x8 b0 = *(const bf16x8*)(Wb + wRowOff + k0 + scol);
            bf16x8 b1 = *(const bf16x8*)(Wb + wRowOff + k0 + scol + 8);
            *(bf16x8*)(ldsA + srow * 32 + scol)     = a0;
            *(bf16x8*)(ldsA + srow * 32 + scol + 8) = a1;
            *(bf16x8*)(ldsB + srow * 32 + scol)     = b0;
            *(bf16x8*)(ldsB + srow * 32 + scol + 8) = b1;
        } else {
            const float* Af = (const float*)A_;
            const float* Wf = (const float*)W_;
            f32x4 va0 = *(const f32x4*)(Af + aRowOff + k0 + scol);
            f32x4 va1 = *(const f32x4*)(Af + aRowOff + k0 + scol + 4);
            f32x4 va2 = *(const f32x4*)(Af + aRowOff + k0 + scol + 8);
            f32x4 va3 = *(const f32x4*)(Af + aRowOff + k0 + scol + 12);
            f32x4 vb0 = *(const f32x4*)(Wf + wRowOff + k0 + scol);
            f32x4 vb1 = *(const f32x4*)(Wf + wRowOff + k0 + scol + 4);
            f32x4 vb2 = *(const f32x4*)(Wf + wRowOff + k0 + scol + 8);
            f32x4 vb3 = *(const f32x4*)(Wf + wRowOff + k0 + scol + 12);
            bf16x8 a0, a1, b0, b1;
#pragma unroll
            for (int j = 0; j < 4; ++j) {
                a0[j]     = f2b(va0[j]); a0[j + 4] = f2b(va1[j]);
                a1[j]     = f2b(va2[j]); a1[j + 4] = f2b(va3[j]);
                b0[j]     = f2b(vb0[j]); b0[j + 4] = f2b(vb1[j]);
                b1[j]     = f2b(vb2[j]); b1[j + 4] = f2b(vb3[j]);
            }
            *(bf16x8*)(ldsA + srow * 32 + scol)     = a0;
            *(bf16x8*)(ldsA + srow * 32 + scol + 8) = a1;
            *(bf16x8*)(ldsB + srow * 32 + scol)     = b0;
            *(bf16x8*)(ldsB + srow * 32 + scol + 8) = b1;
        }
        __syncthreads();

        bf16x8 af[4], bfv[4];
#pragma unroll
        for (int i = 0; i < 4; ++i) {
            af[i]  = *(const bf16x8*)(ldsA + (wm + i * 16 + fr) * 32 + fko);
            bfv[i] = *(const bf16x8*)(ldsB + (wn + i * 16 + fr) * 32 + fko);
        }
#pragma unroll
        for (int i = 0; i < 4; ++i)
#pragma unroll
            for (int j = 0; j < 4; ++j)
                acc[i][j] = __builtin_amdgcn_mfma_f32_16x16x32_bf16(
                    af[i], bfv[j], acc[i][j], 0, 0, 0);
        __syncthreads();
    }

    // epilogue: C/D layout col=lane&15, row=(lane>>4)*4+reg
    const int er = (lane >> 4) * 4;
    const int ec = lane & 15;
    if (isbf) {
        short* C = (short*)C_;
#pragma unroll
        for (int i = 0; i < 4; ++i) {
            const int r0 = blockRow + wm + i * 16 + er;
#pragma unroll
            for (int j = 0; j < 4; ++j) {
                const int c0 = blockCol + wn + j * 16 + ec;
#pragma unroll
                for (int r = 0; r < 4; ++r)
                    C[(size_t)(r0 + r) * N_DIM + c0] = f2b(acc[i][j][r]);
            }
        }
    } else {
        float* C = (float*)C_;
#pragma unroll
        for (int i = 0; i < 4; ++i) {
            const int r0 = blockRow + wm + i * 16 + er;
#pragma unroll
            for (int j = 0; j < 4; ++j) {
                const int c0 = blockCol + wn + j * 16 + ec;
#pragma unroll
                for (int r = 0; r < 4; ++r)
                    C[(size_t)(r0 + r) * N_DIM + c0] = acc[i][j][r];
            }
        }
    }
}

// In-place: y = Y + bias ; per (row, group of 512): groupnorm -> silu -> *mult_w -> silu
// One wave per group: 64 lanes x 8 elements.
__global__ __launch_bounds__(256) void gn_silu_kernel(
    void* __restrict__ Y_,
    const void* __restrict__ bias_,
    const void* __restrict__ gnw_,
    const void* __restrict__ gnb_,
    const void* __restrict__ mw_)
{
    const bool isbf = detect_bf16(gnw_);

    const int lane = threadIdx.x & 63;
    const int wave = threadIdx.x >> 6;
    const unsigned gid = blockIdx.x * 4u + wave;     // 65536 groups
    const unsigned row = gid >> 4;
    const unsigned grp = gid & 15;
    const int col = grp * GSZ + lane * 8;
    const size_t off = (size_t)row * N_DIM + col;

    float y[8], gw[8], gb[8], mw[8];
    if (isbf) {
        const short* Y  = (const short*)Y_;
        bf16x8 v   = *(const bf16x8*)(Y + off);
        bf16x8 bb  = *(const bf16x8*)((const short*)bias_ + col);
        bf16x8 gwv = *(const bf16x8*)((const short*)gnw_ + col);
        bf16x8 gbv = *(const bf16x8*)((const short*)gnb_ + col);
        bf16x8 mwv = *(const bf16x8*)((const short*)mw_ + col);
#pragma unroll
        for (int j = 0; j < 8; ++j) {
            y[j]  = b2f(v[j]) + b2f(bb[j]);
            gw[j] = b2f(gwv[j]); gb[j] = b2f(gbv[j]); mw[j] = b2f(mwv[j]);
        }
    } else {
        const float* Y = (const float*)Y_;
        f32x4 v0 = *(const f32x4*)(Y + off);
        f32x4 v1 = *(const f32x4*)(Y + off + 4);
        f32x4 b0 = *(const f32x4*)((const float*)bias_ + col);
        f32x4 b1 = *(const f32x4*)((const float*)bias_ + col + 4);
        f32x4 w0 = *(const f32x4*)((const float*)gnw_ + col);
        f32x4 w1 = *(const f32x4*)((const float*)gnw_ + col + 4);
        f32x4 g0 = *(const f32x4*)((const float*)gnb_ + col);
        f32x4 g1 = *(const f32x4*)((const float*)gnb_ + col + 4);
        f32x4 m0 = *(const f32x4*)((const float*)mw_ + col);
        f32x4 m1 = *(const f32x4*)((const float*)mw_ + col + 4);
#pragma unroll
        for (int j = 0; j < 4; ++j) {
            y[j]  = v0[j] + b0[j];  y[j + 4]  = v1[j] + b1[j];
            gw[j] = w0[j];          gw[j + 4] = w1[j];
            gb[j] = g0[j];          gb[j + 4] = g1[j];
            mw[j] = m0[j];          mw[j + 4] = m1[j];
        }
    }

    float s = 0.f, s2 = 0.f;
#pragma unroll
    for (int j = 0; j < 8; ++j) { s += y[j]; s2 += y[j] * y[j]; }
#pragma unroll
    for (int d = 1; d < 64; d <<= 1) {
        s  += __shfl_xor(s,  d, 64);
        s2 += __shfl_xor(s2, d, 64);
    }
    const float mean = s * (1.0f / GSZ);
    const float var  = s2 * (1.0f / GSZ) - mean * mean;
    const float inv  = rsqrtf(var + EPSV);

    float r[8];
#pragma unroll
    for (int j = 0; j < 8; ++j) {
        float n  = (y[j] - mean) * inv * gw[j] + gb[j];
        float s1 = n / (1.f + __expf(-n));
        float m  = s1 * mw[j];
        r[j] = m / (1.f + __expf(-m));
    }

    if (isbf) {
        short* Y = (short*)Y_;
        bf16x8 o;
#pragma unroll
        for (int j = 0; j < 8; ++j) o[j] = f2b(r[j]);
        *(bf16x8*)(Y + off) = o;
    } else {
        float* Y = (float*)Y_;
        f32x4 o0, o1;
#pragma unroll
        for (int j = 0; j < 4; ++j) { o0[j] = r[j]; o1[j] = r[j + 4]; }
        *(f32x4*)(Y + off)     = o0;
        *(f32x4*)(Y + off + 4) = o1;
    }
}

extern "C" void kernel_launch(void* const* d_in, const int* in_sizes, int n_in,
                              void* d_out, int out_size, void* d_ws, size_t ws_size,
                              hipStream_t stream)
{
    const void* x   = d_in[0];
    const void* W   = d_in[1];
    const void* b   = d_in[2];
    const void* gnw = d_in[3];
    const void* gnb = d_in[4];
    const void* mw  = d_in[5];

    dim3 ggrid(N_DIM / 128, M_DIM / 128);   // 64 x 32 = 2048 blocks
    gemm_bt_kernel<<<ggrid, 256, 0, stream>>>(x, W, d_out, gnw);

    const int ngroups = M_DIM * NGRP;       // 65536
    gn_silu_kernel<<<ngroups / 4, 256, 0, stream>>>(d_out, b, gnw, gnb, mw);
}

// Round 3
// 401.589 us; speedup vs baseline: 1.4314x; 1.4314x over previous
//
#include <hip/hip_runtime.h>

#define M_DIM 4096
#define N_DIM 8192
#define K_DIM 2048
#define NGRP 16
#define GSZ 512
#define EPSV 1e-5f

#define NX (M_DIM * K_DIM)            // x elems  = 8388608
#define NW (N_DIM * K_DIM)            // W elems  = 16777216
#define NY ((size_t)M_DIM * N_DIM)    // y elems  = 33554432

typedef __attribute__((ext_vector_type(8))) short bf16x8;
typedef __attribute__((ext_vector_type(4))) float f32x4;
typedef __attribute__((ext_vector_type(8))) short shortx8;

__device__ __forceinline__ float b2f(short u) {
    union { unsigned u32; float f; } c;
    c.u32 = ((unsigned)(unsigned short)u) << 16;
    return c.f;
}

__device__ __forceinline__ short f2b(float f) {
    union { float f; unsigned u; } c; c.f = f;
    unsigned r = (c.u + 0x7fffu + ((c.u >> 16) & 1u)) >> 16;
    return (short)r;
}

// ---------------- fp32 -> bf16 bulk convert (x then W, contiguous dst) -------
__global__ __launch_bounds__(256) void convert_kernel(
    const float* __restrict__ x, const float* __restrict__ W,
    short* __restrict__ dst)
{
    const size_t base = ((size_t)blockIdx.x * 256 + threadIdx.x) * 8;
    const float* src = (base < NX) ? (x + base) : (W + (base - NX));
    f32x4 v0 = *(const f32x4*)src;
    f32x4 v1 = *(const f32x4*)(src + 4);
    shortx8 o;
#pragma unroll
    for (int j = 0; j < 4; ++j) { o[j] = f2b(v0[j]); o[j + 4] = f2b(v1[j]); }
    *(shortx8*)(dst + base) = o;
}

// ---------------- m97-structure bf16 GEMM: C = A @ W^T, bf16 out -------------
// 128x128 tile, BK=32, 4 waves x 64x64 quadrant, global_load_lds width=16.
__global__ __launch_bounds__(256) void gemm_bt_bf16_kernel(
    const short* __restrict__ A, const short* __restrict__ W, short* __restrict__ C)
{
    __shared__ __align__(16) short ldsA[128 * 32];
    __shared__ __align__(16) short ldsB[128 * 32];

    const int tid  = threadIdx.x;
    const int lane = tid & 63;
    const int wave = tid >> 6;
    const int blockRow = blockIdx.y * 128;
    const int blockCol = blockIdx.x * 128;

    // staging: chunk j = 16 rows x 32 k; lane covers row j*16+(lane>>2), k (lane&3)*8
    // LDS offset from chunk base = lane*8 shorts = lane*16 B (wave-uniform base + lane*16) ✓
    const int sub = lane >> 2;
    const int kq  = (lane & 3) * 8;

    const int wm  = (wave >> 1) * 64;
    const int wn  = (wave & 1) * 64;
    const int fr  = lane & 15;
    const int fko = (lane >> 4) * 8;

    f32x4 acc[4][4] = {};

    for (int k0 = 0; k0 < K_DIM; k0 += 32) {
#pragma unroll
        for (int c = 0; c < 4; ++c) {
            const int chunk = wave * 4 + c;     // 0..7 = A, 8..15 = B
            const int j = chunk & 7;
            const int row = j * 16 + sub;
            const short* g;
            short* l;
            if (chunk < 8) {
                g = A + (size_t)(blockRow + row) * K_DIM + k0 + kq;
                l = ldsA + j * 512;
            } else {
                g = W + (size_t)(blockCol + row) * K_DIM + k0 + kq;
                l = ldsB + j * 512;
            }
            __builtin_amdgcn_global_load_lds(
                (const __attribute__((address_space(1))) void*)g,
                (__attribute__((address_space(3))) void*)l,
                16, 0, 0);
        }
        __syncthreads();

        bf16x8 af[4], bfv[4];
#pragma unroll
        for (int i = 0; i < 4; ++i) {
            af[i]  = *(const bf16x8*)(ldsA + (wm + i * 16 + fr) * 32 + fko);
            bfv[i] = *(const bf16x8*)(ldsB + (wn + i * 16 + fr) * 32 + fko);
        }
#pragma unroll
        for (int i = 0; i < 4; ++i)
#pragma unroll
            for (int j = 0; j < 4; ++j)
                acc[i][j] = __builtin_amdgcn_mfma_f32_16x16x32_bf16(
                    af[i], bfv[j], acc[i][j], 0, 0, 0);
        __syncthreads();
    }

    // C/D layout: col=lane&15, row=(lane>>4)*4+reg
    const int er = (lane >> 4) * 4;
    const int ec = lane & 15;
#pragma unroll
    for (int i = 0; i < 4; ++i) {
        const int r0 = blockRow + wm + i * 16 + er;
#pragma unroll
        for (int j = 0; j < 4; ++j) {
            const int c0 = blockCol + wn + j * 16 + ec;
#pragma unroll
            for (int r = 0; r < 4; ++r)
                C[(size_t)(r0 + r) * N_DIM + c0] = f2b(acc[i][j][r]);
        }
    }
}

// ------------- GN epilogue: read bf16 y, +bias, groupnorm, silu*mw*silu, fp32 out
__global__ __launch_bounds__(256) void gn_silu_bf16_kernel(
    const short* __restrict__ Y,
    const float* __restrict__ bias,
    const float* __restrict__ gnw,
    const float* __restrict__ gnb,
    const float* __restrict__ mw,
    float* __restrict__ out)
{
    const int lane = threadIdx.x & 63;
    const int wave = threadIdx.x >> 6;
    const unsigned gid = blockIdx.x * 4u + wave;     // 65536 groups
    const unsigned row = gid >> 4;
    const unsigned grp = gid & 15;
    const int col = grp * GSZ + lane * 8;
    const size_t off = (size_t)row * N_DIM + col;

    bf16x8 v = *(const bf16x8*)(Y + off);
    f32x4 b0 = *(const f32x4*)(bias + col);
    f32x4 b1 = *(const f32x4*)(bias + col + 4);

    float y[8];
    float s = 0.f, s2 = 0.f;
#pragma unroll
    for (int j = 0; j < 8; ++j) {
        y[j] = b2f(v[j]) + (j < 4 ? b0[j] : b1[j - 4]);
        s  += y[j];
        s2 += y[j] * y[j];
    }
#pragma unroll
    for (int d = 1; d < 64; d <<= 1) {
        s  += __shfl_xor(s,  d, 64);
        s2 += __shfl_xor(s2, d, 64);
    }
    const float mean = s * (1.0f / GSZ);
    const float var  = s2 * (1.0f / GSZ) - mean * mean;
    const float inv  = rsqrtf(var + EPSV);

    f32x4 w0 = *(const f32x4*)(gnw + col);
    f32x4 w1 = *(const f32x4*)(gnw + col + 4);
    f32x4 g0 = *(const f32x4*)(gnb + col);
    f32x4 g1 = *(const f32x4*)(gnb + col + 4);
    f32x4 m0 = *(const f32x4*)(mw + col);
    f32x4 m1 = *(const f32x4*)(mw + col + 4);

    f32x4 o0, o1;
#pragma unroll
    for (int j = 0; j < 8; ++j) {
        float gwv = j < 4 ? w0[j] : w1[j - 4];
        float gbv = j < 4 ? g0[j] : g1[j - 4];
        float mwv = j < 4 ? m0[j] : m1[j - 4];
        float n  = (y[j] - mean) * inv * gwv + gbv;
        float s1 = n / (1.f + __expf(-n));
        float m  = s1 * mwv;
        float r  = m / (1.f + __expf(-m));
        if (j < 4) o0[j] = r; else o1[j - 4] = r;
    }
    *(f32x4*)(out + off)     = o0;
    *(f32x4*)(out + off + 4) = o1;
}

// ================== fallback path (round-2, known-good) ======================
__global__ __launch_bounds__(256) void gemm_bt_f32_kernel(
    const float* __restrict__ A, const float* __restrict__ W, float* __restrict__ C)
{
    __shared__ __align__(16) short ldsA[128 * 32];
    __shared__ __align__(16) short ldsB[128 * 32];

    const int tid  = threadIdx.x;
    const int lane = tid & 63;
    const int wave = tid >> 6;
    const int blockRow = blockIdx.y * 128;
    const int blockCol = blockIdx.x * 128;
    const int srow = tid >> 1;
    const int scol = (tid & 1) * 16;
    const int wm  = (wave >> 1) * 64;
    const int wn  = (wave & 1) * 64;
    const int fr  = lane & 15;
    const int fko = (lane >> 4) * 8;

    f32x4 acc[4][4] = {};
    const size_t aRowOff = (size_t)(blockRow + srow) * K_DIM;
    const size_t wRowOff = (size_t)(blockCol + srow) * K_DIM;

    for (int k0 = 0; k0 < K_DIM; k0 += 32) {
        f32x4 va0 = *(const f32x4*)(A + aRowOff + k0 + scol);
        f32x4 va1 = *(const f32x4*)(A + aRowOff + k0 + scol + 4);
        f32x4 va2 = *(const f32x4*)(A + aRowOff + k0 + scol + 8);
        f32x4 va3 = *(const f32x4*)(A + aRowOff + k0 + scol + 12);
        f32x4 vb0 = *(const f32x4*)(W + wRowOff + k0 + scol);
        f32x4 vb1 = *(const f32x4*)(W + wRowOff + k0 + scol + 4);
        f32x4 vb2 = *(const f32x4*)(W + wRowOff + k0 + scol + 8);
        f32x4 vb3 = *(const f32x4*)(W + wRowOff + k0 + scol + 12);
        bf16x8 a0, a1, b0, b1;
#pragma unroll
        for (int j = 0; j < 4; ++j) {
            a0[j] = f2b(va0[j]); a0[j + 4] = f2b(va1[j]);
            a1[j] = f2b(va2[j]); a1[j + 4] = f2b(va3[j]);
            b0[j] = f2b(vb0[j]); b0[j + 4] = f2b(vb1[j]);
            b1[j] = f2b(vb2[j]); b1[j + 4] = f2b(vb3[j]);
        }
        *(bf16x8*)(ldsA + srow * 32 + scol)     = a0;
        *(bf16x8*)(ldsA + srow * 32 + scol + 8) = a1;
        *(bf16x8*)(ldsB + srow * 32 + scol)     = b0;
        *(bf16x8*)(ldsB + srow * 32 + scol + 8) = b1;
        __syncthreads();

        bf16x8 af[4], bfv[4];
#pragma unroll
        for (int i = 0; i < 4; ++i) {
            af[i]  = *(const bf16x8*)(ldsA + (wm + i * 16 + fr) * 32 + fko);
            bfv[i] = *(const bf16x8*)(ldsB + (wn + i * 16 + fr) * 32 + fko);
        }
#pragma unroll
        for (int i = 0; i < 4; ++i)
#pragma unroll
            for (int j = 0; j < 4; ++j)
                acc[i][j] = __builtin_amdgcn_mfma_f32_16x16x32_bf16(
                    af[i], bfv[j], acc[i][j], 0, 0, 0);
        __syncthreads();
    }

    const int er = (lane >> 4) * 4;
    const int ec = lane & 15;
#pragma unroll
    for (int i = 0; i < 4; ++i) {
        const int r0 = blockRow + wm + i * 16 + er;
#pragma unroll
        for (int j = 0; j < 4; ++j) {
            const int c0 = blockCol + wn + j * 16 + ec;
#pragma unroll
            for (int r = 0; r < 4; ++r)
                C[(size_t)(r0 + r) * N_DIM + c0] = acc[i][j][r];
        }
    }
}

__global__ __launch_bounds__(256) void gn_silu_f32_kernel(
    float* __restrict__ Y,
    const float* __restrict__ bias,
    const float* __restrict__ gnw,
    const float* __restrict__ gnb,
    const float* __restrict__ mw)
{
    const int lane = threadIdx.x & 63;
    const int wave = threadIdx.x >> 6;
    const unsigned gid = blockIdx.x * 4u + wave;
    const unsigned row = gid >> 4;
    const unsigned grp = gid & 15;
    const int col = grp * GSZ + lane * 8;
    const size_t off = (size_t)row * N_DIM + col;

    f32x4 v0 = *(const f32x4*)(Y + off);
    f32x4 v1 = *(const f32x4*)(Y + off + 4);
    f32x4 b0 = *(const f32x4*)(bias + col);
    f32x4 b1 = *(const f32x4*)(bias + col + 4);

    float y[8];
    float s = 0.f, s2 = 0.f;
#pragma unroll
    for (int j = 0; j < 8; ++j) {
        y[j] = (j < 4 ? v0[j] + b0[j] : v1[j - 4] + b1[j - 4]);
        s += y[j]; s2 += y[j] * y[j];
    }
#pragma unroll
    for (int d = 1; d < 64; d <<= 1) {
        s  += __shfl_xor(s,  d, 64);
        s2 += __shfl_xor(s2, d, 64);
    }
    const float mean = s * (1.0f / GSZ);
    const float var  = s2 * (1.0f / GSZ) - mean * mean;
    const float inv  = rsqrtf(var + EPSV);

    f32x4 w0 = *(const f32x4*)(gnw + col);
    f32x4 w1 = *(const f32x4*)(gnw + col + 4);
    f32x4 g0 = *(const f32x4*)(gnb + col);
    f32x4 g1 = *(const f32x4*)(gnb + col + 4);
    f32x4 m0 = *(const f32x4*)(mw + col);
    f32x4 m1 = *(const f32x4*)(mw + col + 4);

    f32x4 o0, o1;
#pragma unroll
    for (int j = 0; j < 8; ++j) {
        float gwv = j < 4 ? w0[j] : w1[j - 4];
        float gbv = j < 4 ? g0[j] : g1[j - 4];
        float mwv = j < 4 ? m0[j] : m1[j - 4];
        float n  = (y[j] - mean) * inv * gwv + gbv;
        float s1 = n / (1.f + __expf(-n));
        float m  = s1 * mwv;
        float r  = m / (1.f + __expf(-m));
        if (j < 4) o0[j] = r; else o1[j - 4] = r;
    }
    *(f32x4*)(Y + off)     = o0;
    *(f32x4*)(Y + off + 4) = o1;
}

extern "C" void kernel_launch(void* const* d_in, const int* in_sizes, int n_in,
                              void* d_out, int out_size, void* d_ws, size_t ws_size,
                              hipStream_t stream)
{
    const float* x   = (const float*)d_in[0];
    const float* W   = (const float*)d_in[1];
    const float* b   = (const float*)d_in[2];
    const float* gnw = (const float*)d_in[3];
    const float* gnb = (const float*)d_in[4];
    const float* mw  = (const float*)d_in[5];
    float* out = (float*)d_out;

    // ws layout: xb[NX] | Wb[NW] | yb[NY]  (bf16 shorts) = 117,440,512 bytes
    const size_t need = ((size_t)NX + NW + NY) * sizeof(short);
    dim3 ggrid(N_DIM / 128, M_DIM / 128);   // 64 x 32 = 2048 blocks
    const int ngroups = M_DIM * NGRP;       // 65536

    if (ws_size >= need) {
        short* xb = (short*)d_ws;
        short* Wb = xb + NX;
        short* yb = Wb + NW;

        convert_kernel<<<(NX + NW) / (256 * 8), 256, 0, stream>>>(x, W, xb);
        gemm_bt_bf16_kernel<<<ggrid, 256, 0, stream>>>(xb, Wb, yb);
        gn_silu_bf16_kernel<<<ngroups / 4, 256, 0, stream>>>(yb, b, gnw, gnb, mw, out);
    } else {
        gemm_bt_f32_kernel<<<ggrid, 256, 0, stream>>>(x, W, out);
        gn_silu_f32_kernel<<<ngroups / 4, 256, 0, stream>>>(out, b, gnw, gnb, mw);
    }
}

// Round 4
// 401.110 us; speedup vs baseline: 1.4331x; 1.0012x over previous
//
#include <hip/hip_runtime.h>

#define M_DIM 4096
#define N_DIM 8192
#define K_DIM 2048
#define NGRP 16
#define GSZ 512
#define EPSV 1e-5f

#define NX (M_DIM * K_DIM)            // x elems  = 8388608
#define NW (N_DIM * K_DIM)            // W elems  = 16777216
#define NY ((size_t)M_DIM * N_DIM)    // y elems  = 33554432

typedef __attribute__((ext_vector_type(8))) short bf16x8;
typedef __attribute__((ext_vector_type(4))) float f32x4;
typedef __attribute__((ext_vector_type(8))) short shortx8;

__device__ __forceinline__ float b2f(short u) {
    union { unsigned u32; float f; } c;
    c.u32 = ((unsigned)(unsigned short)u) << 16;
    return c.f;
}

__device__ __forceinline__ short f2b(float f) {
    union { float f; unsigned u; } c; c.f = f;
    unsigned r = (c.u + 0x7fffu + ((c.u >> 16) & 1u)) >> 16;
    return (short)r;
}

// ---------------- fp32 -> bf16 bulk convert (x then W, contiguous dst) -------
// 32 elems/thread for ILP (4 x (two 16B loads + one 16B store)).
__global__ __launch_bounds__(256) void convert_kernel(
    const float* __restrict__ x, const float* __restrict__ W,
    short* __restrict__ dst)
{
    const size_t base = ((size_t)blockIdx.x * 256 + threadIdx.x) * 32;
    // NX divisible by 32, so a thread never straddles the x/W boundary.
    const float* src = (base < NX) ? (x + base) : (W + (base - NX));
    f32x4 v[8];
#pragma unroll
    for (int c = 0; c < 8; ++c) v[c] = *(const f32x4*)(src + c * 4);
#pragma unroll
    for (int c = 0; c < 4; ++c) {
        shortx8 o;
#pragma unroll
        for (int j = 0; j < 4; ++j) {
            o[j]     = f2b(v[2 * c][j]);
            o[j + 4] = f2b(v[2 * c + 1][j]);
        }
        *(shortx8*)(dst + base + c * 8) = o;
    }
}

// ---------------- m97-structure bf16 GEMM + LDS XOR swizzle ------------------
// C = A @ W^T, bf16 in/out. 128x128 tile, BK=32, 4 waves x 64x64 quadrant,
// global_load_lds width=16. LDS k-block swizzle: p_kb = kb ^ ((row>>1)&3),
// applied at stage (global src index) and read (fragment index) — kills the
// 8-way bank conflict of the linear layout (16B-granular, coalescing intact).
__global__ __launch_bounds__(256) void gemm_bt_bf16_kernel(
    const short* __restrict__ A, const short* __restrict__ W, short* __restrict__ C)
{
    __shared__ __align__(16) short ldsA[128 * 32];
    __shared__ __align__(16) short ldsB[128 * 32];

    const int tid  = threadIdx.x;
    const int lane = tid & 63;
    const int wave = tid >> 6;
    const int blockRow = blockIdx.y * 128;
    const int blockCol = blockIdx.x * 128;

    // staging: chunk j covers rows j*16..j*16+15, all 32 k.
    // physical LDS slot of lane = chunk_base + lane*16B = (row, p_kb)
    //   with row = j*16 + (lane>>2), p_kb = lane&3.
    // swizzle s(row) = (row>>1)&3 = (lane>>3)&3  (j*16 contributes 0 mod 4).
    const int sub = lane >> 2;
    const int kq  = (((lane & 3) ^ ((lane >> 3) & 3))) * 8;  // logical k offset

    const int wm  = (wave >> 1) * 64;
    const int wn  = (wave & 1) * 64;
    const int fr  = lane & 15;
    // fragment read: logical kb = lane>>4; physical = kb ^ ((fr>>1)&3)
    const int fko = (((lane >> 4) ^ ((fr >> 1) & 3))) * 8;

    f32x4 acc[4][4] = {};

    for (int k0 = 0; k0 < K_DIM; k0 += 32) {
#pragma unroll
        for (int c = 0; c < 4; ++c) {
            const int chunk = wave * 4 + c;     // 0..7 = A, 8..15 = B
            const int j = chunk & 7;
            const int row = j * 16 + sub;
            const short* g;
            short* l;
            if (chunk < 8) {
                g = A + (size_t)(blockRow + row) * K_DIM + k0 + kq;
                l = ldsA + j * 512;
            } else {
                g = W + (size_t)(blockCol + row) * K_DIM + k0 + kq;
                l = ldsB + j * 512;
            }
            __builtin_amdgcn_global_load_lds(
                (const __attribute__((address_space(1))) void*)g,
                (__attribute__((address_space(3))) void*)l,
                16, 0, 0);
        }
        __syncthreads();

        bf16x8 af[4], bfv[4];
#pragma unroll
        for (int i = 0; i < 4; ++i) {
            af[i]  = *(const bf16x8*)(ldsA + (wm + i * 16 + fr) * 32 + fko);
            bfv[i] = *(const bf16x8*)(ldsB + (wn + i * 16 + fr) * 32 + fko);
        }
#pragma unroll
        for (int i = 0; i < 4; ++i)
#pragma unroll
            for (int j = 0; j < 4; ++j)
                acc[i][j] = __builtin_amdgcn_mfma_f32_16x16x32_bf16(
                    af[i], bfv[j], acc[i][j], 0, 0, 0);
        __syncthreads();
    }

    // C/D layout: col=lane&15, row=(lane>>4)*4+reg
    const int er = (lane >> 4) * 4;
    const int ec = lane & 15;
#pragma unroll
    for (int i = 0; i < 4; ++i) {
        const int r0 = blockRow + wm + i * 16 + er;
#pragma unroll
        for (int j = 0; j < 4; ++j) {
            const int c0 = blockCol + wn + j * 16 + ec;
#pragma unroll
            for (int r = 0; r < 4; ++r)
                C[(size_t)(r0 + r) * N_DIM + c0] = f2b(acc[i][j][r]);
        }
    }
}

// ------------- GN epilogue: read bf16 y, +bias, groupnorm, silu*mw*silu, fp32 out
__global__ __launch_bounds__(256) void gn_silu_bf16_kernel(
    const short* __restrict__ Y,
    const float* __restrict__ bias,
    const float* __restrict__ gnw,
    const float* __restrict__ gnb,
    const float* __restrict__ mw,
    float* __restrict__ out)
{
    const int lane = threadIdx.x & 63;
    const int wave = threadIdx.x >> 6;
    const unsigned gid = blockIdx.x * 4u + wave;     // 65536 groups
    const unsigned row = gid >> 4;
    const unsigned grp = gid & 15;
    const int col = grp * GSZ + lane * 8;
    const size_t off = (size_t)row * N_DIM + col;

    bf16x8 v = *(const bf16x8*)(Y + off);
    f32x4 b0 = *(const f32x4*)(bias + col);
    f32x4 b1 = *(const f32x4*)(bias + col + 4);

    float y[8];
    float s = 0.f, s2 = 0.f;
#pragma unroll
    for (int j = 0; j < 8; ++j) {
        y[j] = b2f(v[j]) + (j < 4 ? b0[j] : b1[j - 4]);
        s  += y[j];
        s2 += y[j] * y[j];
    }
#pragma unroll
    for (int d = 1; d < 64; d <<= 1) {
        s  += __shfl_xor(s,  d, 64);
        s2 += __shfl_xor(s2, d, 64);
    }
    const float mean = s * (1.0f / GSZ);
    const float var  = s2 * (1.0f / GSZ) - mean * mean;
    const float inv  = rsqrtf(var + EPSV);

    f32x4 w0 = *(const f32x4*)(gnw + col);
    f32x4 w1 = *(const f32x4*)(gnw + col + 4);
    f32x4 g0 = *(const f32x4*)(gnb + col);
    f32x4 g1 = *(const f32x4*)(gnb + col + 4);
    f32x4 m0 = *(const f32x4*)(mw + col);
    f32x4 m1 = *(const f32x4*)(mw + col + 4);

    f32x4 o0, o1;
#pragma unroll
    for (int j = 0; j < 8; ++j) {
        float gwv = j < 4 ? w0[j] : w1[j - 4];
        float gbv = j < 4 ? g0[j] : g1[j - 4];
        float mwv = j < 4 ? m0[j] : m1[j - 4];
        float n  = (y[j] - mean) * inv * gwv + gbv;
        float s1 = n / (1.f + __expf(-n));
        float m  = s1 * mwv;
        float r  = m / (1.f + __expf(-m));
        if (j < 4) o0[j] = r; else o1[j - 4] = r;
    }
    *(f32x4*)(out + off)     = o0;
    *(f32x4*)(out + off + 4) = o1;
}

// ================== fallback path (round-2, known-good) ======================
__global__ __launch_bounds__(256) void gemm_bt_f32_kernel(
    const float* __restrict__ A, const float* __restrict__ W, float* __restrict__ C)
{
    __shared__ __align__(16) short ldsA[128 * 32];
    __shared__ __align__(16) short ldsB[128 * 32];

    const int tid  = threadIdx.x;
    const int lane = tid & 63;
    const int wave = tid >> 6;
    const int blockRow = blockIdx.y * 128;
    const int blockCol = blockIdx.x * 128;
    const int srow = tid >> 1;
    const int scol = (tid & 1) * 16;
    const int wm  = (wave >> 1) * 64;
    const int wn  = (wave & 1) * 64;
    const int fr  = lane & 15;
    const int fko = (lane >> 4) * 8;

    f32x4 acc[4][4] = {};
    const size_t aRowOff = (size_t)(blockRow + srow) * K_DIM;
    const size_t wRowOff = (size_t)(blockCol + srow) * K_DIM;

    for (int k0 = 0; k0 < K_DIM; k0 += 32) {
        f32x4 va0 = *(const f32x4*)(A + aRowOff + k0 + scol);
        f32x4 va1 = *(const f32x4*)(A + aRowOff + k0 + scol + 4);
        f32x4 va2 = *(const f32x4*)(A + aRowOff + k0 + scol + 8);
        f32x4 va3 = *(const f32x4*)(A + aRowOff + k0 + scol + 12);
        f32x4 vb0 = *(const f32x4*)(W + wRowOff + k0 + scol);
        f32x4 vb1 = *(const f32x4*)(W + wRowOff + k0 + scol + 4);
        f32x4 vb2 = *(const f32x4*)(W + wRowOff + k0 + scol + 8);
        f32x4 vb3 = *(const f32x4*)(W + wRowOff + k0 + scol + 12);
        bf16x8 a0, a1, b0, b1;
#pragma unroll
        for (int j = 0; j < 4; ++j) {
            a0[j] = f2b(va0[j]); a0[j + 4] = f2b(va1[j]);
            a1[j] = f2b(va2[j]); a1[j + 4] = f2b(va3[j]);
            b0[j] = f2b(vb0[j]); b0[j + 4] = f2b(vb1[j]);
            b1[j] = f2b(vb2[j]); b1[j + 4] = f2b(vb3[j]);
        }
        *(bf16x8*)(ldsA + srow * 32 + scol)     = a0;
        *(bf16x8*)(ldsA + srow * 32 + scol + 8) = a1;
        *(bf16x8*)(ldsB + srow * 32 + scol)     = b0;
        *(bf16x8*)(ldsB + srow * 32 + scol + 8) = b1;
        __syncthreads();

        bf16x8 af[4], bfv[4];
#pragma unroll
        for (int i = 0; i < 4; ++i) {
            af[i]  = *(const bf16x8*)(ldsA + (wm + i * 16 + fr) * 32 + fko);
            bfv[i] = *(const bf16x8*)(ldsB + (wn + i * 16 + fr) * 32 + fko);
        }
#pragma unroll
        for (int i = 0; i < 4; ++i)
#pragma unroll
            for (int j = 0; j < 4; ++j)
                acc[i][j] = __builtin_amdgcn_mfma_f32_16x16x32_bf16(
                    af[i], bfv[j], acc[i][j], 0, 0, 0);
        __syncthreads();
    }

    const int er = (lane >> 4) * 4;
    const int ec = lane & 15;
#pragma unroll
    for (int i = 0; i < 4; ++i) {
        const int r0 = blockRow + wm + i * 16 + er;
#pragma unroll
        for (int j = 0; j < 4; ++j) {
            const int c0 = blockCol + wn + j * 16 + ec;
#pragma unroll
            for (int r = 0; r < 4; ++r)
                C[(size_t)(r0 + r) * N_DIM + c0] = acc[i][j][r];
        }
    }
}

__global__ __launch_bounds__(256) void gn_silu_f32_kernel(
    float* __restrict__ Y,
    const float* __restrict__ bias,
    const float* __restrict__ gnw,
    const float* __restrict__ gnb,
    const float* __restrict__ mw)
{
    const int lane = threadIdx.x & 63;
    const int wave = threadIdx.x >> 6;
    const unsigned gid = blockIdx.x * 4u + wave;
    const unsigned row = gid >> 4;
    const unsigned grp = gid & 15;
    const int col = grp * GSZ + lane * 8;
    const size_t off = (size_t)row * N_DIM + col;

    f32x4 v0 = *(const f32x4*)(Y + off);
    f32x4 v1 = *(const f32x4*)(Y + off + 4);
    f32x4 b0 = *(const f32x4*)(bias + col);
    f32x4 b1 = *(const f32x4*)(bias + col + 4);

    float y[8];
    float s = 0.f, s2 = 0.f;
#pragma unroll
    for (int j = 0; j < 8; ++j) {
        y[j] = (j < 4 ? v0[j] + b0[j] : v1[j - 4] + b1[j - 4]);
        s += y[j]; s2 += y[j] * y[j];
    }
#pragma unroll
    for (int d = 1; d < 64; d <<= 1) {
        s  += __shfl_xor(s,  d, 64);
        s2 += __shfl_xor(s2, d, 64);
    }
    const float mean = s * (1.0f / GSZ);
    const float var  = s2 * (1.0f / GSZ) - mean * mean;
    const float inv  = rsqrtf(var + EPSV);

    f32x4 w0 = *(const f32x4*)(gnw + col);
    f32x4 w1 = *(const f32x4*)(gnw + col + 4);
    f32x4 g0 = *(const f32x4*)(gnb + col);
    f32x4 g1 = *(const f32x4*)(gnb + col + 4);
    f32x4 m0 = *(const f32x4*)(mw + col);
    f32x4 m1 = *(const f32x4*)(mw + col + 4);

    f32x4 o0, o1;
#pragma unroll
    for (int j = 0; j < 8; ++j) {
        float gwv = j < 4 ? w0[j] : w1[j - 4];
        float gbv = j < 4 ? g0[j] : g1[j - 4];
        float mwv = j < 4 ? m0[j] : m1[j - 4];
        float n  = (y[j] - mean) * inv * gwv + gbv;
        float s1 = n / (1.f + __expf(-n));
        float m  = s1 * mwv;
        float r  = m / (1.f + __expf(-m));
        if (j < 4) o0[j] = r; else o1[j - 4] = r;
    }
    *(f32x4*)(Y + off)     = o0;
    *(f32x4*)(Y + off + 4) = o1;
}

extern "C" void kernel_launch(void* const* d_in, const int* in_sizes, int n_in,
                              void* d_out, int out_size, void* d_ws, size_t ws_size,
                              hipStream_t stream)
{
    const float* x   = (const float*)d_in[0];
    const float* W   = (const float*)d_in[1];
    const float* b   = (const float*)d_in[2];
    const float* gnw = (const float*)d_in[3];
    const float* gnb = (const float*)d_in[4];
    const float* mw  = (const float*)d_in[5];
    float* out = (float*)d_out;

    // ws layout: xb[NX] | Wb[NW] | yb[NY]  (bf16 shorts) = 117,440,512 bytes
    const size_t need = ((size_t)NX + NW + NY) * sizeof(short);
    dim3 ggrid(N_DIM / 128, M_DIM / 128);   // 64 x 32 = 2048 blocks
    const int ngroups = M_DIM * NGRP;       // 65536

    if (ws_size >= need) {
        short* xb = (short*)d_ws;
        short* Wb = xb + NX;
        short* yb = Wb + NW;

        convert_kernel<<<(NX + NW) / (256 * 32), 256, 0, stream>>>(x, W, xb);
        gemm_bt_bf16_kernel<<<ggrid, 256, 0, stream>>>(xb, Wb, yb);
        gn_silu_bf16_kernel<<<ngroups / 4, 256, 0, stream>>>(yb, b, gnw, gnb, mw, out);
    } else {
        gemm_bt_f32_kernel<<<ggrid, 256, 0, stream>>>(x, W, out);
        gn_silu_f32_kernel<<<ngroups / 4, 256, 0, stream>>>(out, b, gnw, gnb, mw);
    }
}